// Round 13
// baseline (2854.889 us; speedup 1.0000x reference)
//
#include <hip/hip_runtime.h>
#include <hip/hip_fp16.h>

#define TPB 512

typedef _Float16 f16x8 __attribute__((ext_vector_type(8)));
typedef float f32x4 __attribute__((ext_vector_type(4)));

__device__ __forceinline__ float softplus_f(float x) {
    return fmaxf(x, 0.f) + __logf(1.f + __expf(-fabsf(x)));
}
__device__ __forceinline__ float tanh_f(float x) {
    float e = __expf(2.f * x);
    return 1.f - 2.f / (e + 1.f);
}
__device__ __forceinline__ float sigmoid_f(float x) {
    return 1.f / (1.f + __expf(-x));
}

__device__ __forceinline__ f32x4 mfma16(f16x8 a, f16x8 b, f32x4 c) {
    return __builtin_amdgcn_mfma_f32_16x16x32_f16(a, b, c, 0, 0, 0);
}

// DPP add-reduce: 0xB1 = quad_perm xor1, 0x4E = quad_perm xor2,
// 0x141 = row_half_mirror (all involutions, direction-safe) [R5-validated]
template <int CTRL>
__device__ __forceinline__ float dpp_add(float x) {
    int m = __builtin_amdgcn_update_dpp(0, __builtin_bit_cast(int, x), CTRL, 0xF, 0xF, true);
    return x + __builtin_bit_cast(float, m);
}

__global__ __launch_bounds__(TPB, 1) void ncde_kernel(
    const float* __restrict__ timestamps, const float* __restrict__ obs,
    const float* __restrict__ coef_d, const float* __restrict__ coef_c,
    const float* __restrict__ coef_b, const float* __restrict__ coef_a,
    const float* __restrict__ gru_wih, const float* __restrict__ gru_whh,
    const float* __restrict__ gru_bih, const float* __restrict__ gru_bhh,
    const float* __restrict__ gru_lin_w,
    const float* __restrict__ ie_w0, const float* __restrict__ ie_b0,
    const float* __restrict__ ie_wh, const float* __restrict__ ie_bh,
    const float* __restrict__ ie_wout, const float* __restrict__ ie_bout,
    const float* __restrict__ vf_w0, const float* __restrict__ vf_b0,
    const float* __restrict__ vf_wh, const float* __restrict__ vf_bh,
    const float* __restrict__ vf_wout, const float* __restrict__ vf_bout,
    const float* __restrict__ dec_w0, const float* __restrict__ dec_b0,
    const float* __restrict__ dec_wh, const float* __restrict__ dec_bh,
    const float* __restrict__ dec_wout, const float* __restrict__ dec_bout,
    float* __restrict__ out)
{
    const int b = blockIdx.x;
    const int tid = threadIdx.x;
    const int lane = tid & 63, wv = tid >> 6;
    const int m16 = lane & 15, g4 = lane >> 4;

    __shared__ __align__(16) float s_ysall[128][64];   // all y states (for decoder)
    __shared__ __align__(16) float s_whh[192 * 65];    // GRU Whh, padded rows
    __shared__ __align__(16) float s_wih[192 * 9];     // GRU Wih, padded
    __shared__ __align__(16) float s_obs[24 * 8];
    __shared__ float s_gi[192];
    __shared__ float s_gh[192];
    __shared__ __align__(16) float s_y[64];            // ODE state (f32)
    __shared__ __align__(16) __half s_ysbh[64];        // stage input ys (fp16, mfma B)
    __shared__ __align__(16) __half s_h1h[128];
    __shared__ __align__(16) __half s_h2h[128];
    __shared__ __align__(16) float s_V[1024];          // raw Wout@h2 (pre-bias/tanh)
    __shared__ __align__(16) float s_k[6][64];
    __shared__ float s_bi[16], s_ci[16], s_di[16];
    __shared__ __align__(16) float s_v48[48];
    __shared__ float s_m1[128], s_m2[128];

    // ---- stage GRU weights into LDS ----
    for (int idx = tid; idx < 192 * 64; idx += TPB)
        s_whh[(idx >> 6) * 65 + (idx & 63)] = gru_whh[idx];
    for (int idx = tid; idx < 192 * 8; idx += TPB)
        s_wih[(idx >> 3) * 9 + (idx & 7)] = gru_wih[idx];
    if (tid < 24 * 8) s_obs[tid] = obs[(size_t)b * 192 + tid];
    const float bih_r = (tid < 192) ? gru_bih[tid] : 0.f;
    const float bhh_r = (tid < 192) ? gru_bhh[tid] : 0.f;
    if (tid < 64) s_y[tid] = 0.f;   // GRU hidden init
    __syncthreads();

    // ---- GRU over 24 steps ----
    for (int step = 0; step < 24; ++step) {
        if (tid < 192) {
            float gi = bih_r;
            const float* wr = &s_wih[tid * 9];
            const float* xr = &s_obs[step * 8];
#pragma unroll
            for (int j = 0; j < 8; ++j) gi = fmaf(wr[j], xr[j], gi);
            float g0 = bhh_r, g1 = 0.f, g2 = 0.f, g3 = 0.f;
            const float* hr = &s_whh[tid * 65];
#pragma unroll 4
            for (int j = 0; j < 64; j += 4) {
                g0 = fmaf(hr[j + 0], s_y[j + 0], g0);
                g1 = fmaf(hr[j + 1], s_y[j + 1], g1);
                g2 = fmaf(hr[j + 2], s_y[j + 2], g2);
                g3 = fmaf(hr[j + 3], s_y[j + 3], g3);
            }
            s_gi[tid] = gi;
            s_gh[tid] = (g0 + g1) + (g2 + g3);
        }
        __syncthreads();
        if (tid < 64) {
            float rg = sigmoid_f(s_gi[tid] + s_gh[tid]);
            float zg = sigmoid_f(s_gi[64 + tid] + s_gh[64 + tid]);
            float ng = tanh_f(s_gi[128 + tid] + rg * s_gh[128 + tid]);
            s_y[tid] = (1.f - zg) * ng + zg * s_y[tid];
        }
        __syncthreads();
    }

    // ---- enc = gru_lin_w @ hT ; concat with x0 = coef_a[b,0,:] ----
    if (tid < 32) {
        float e = 0.f;
        const float* wr = gru_lin_w + tid * 64;
        for (int j = 0; j < 64; ++j) e = fmaf(wr[j], s_y[j], e);
        s_v48[tid] = e;
    } else if (tid < 48) {
        s_v48[tid] = coef_a[(size_t)b * 127 * 16 + (tid - 32)];
    }
    __syncthreads();

    // ---- initial-embedding MLP: 48 -> 128 -> 128 -> 64 ----
    if (tid < 128) {
        float a = ie_b0[tid];
        const float* wr = ie_w0 + tid * 48;
        for (int j = 0; j < 48; ++j) a = fmaf(wr[j], s_v48[j], a);
        s_m1[tid] = fmaxf(a, 0.f);
    }
    __syncthreads();
    if (tid < 128) {
        float a = ie_bh[tid];
        const float* wr = ie_wh + tid * 128;
        for (int j = 0; j < 128; ++j) a = fmaf(wr[j], s_m1[j], a);
        s_m2[tid] = fmaxf(a, 0.f);
    }
    __syncthreads();
    if (tid < 64) {
        float a = ie_bout[tid];
        const float* wr = ie_wout + tid * 128;
        for (int j = 0; j < 128; ++j) a = fmaf(wr[j], s_m2[j], a);
        s_y[tid] = a;
        s_ysbh[tid] = __float2half_rn(a);
        s_ysall[0][tid] = a;
    }
    __syncthreads();

    // ---- MFMA A-fragments for vf weights (fp16) — mappings validated in R9 ----
    // A[m][k]: m = tile_row_base + m16, k = f*32 + g4*8 + j
    f16x8 aw0[2], awh[4], awq[8][4];
    {
        const int row = wv * 16 + m16;
#pragma unroll
        for (int f = 0; f < 2; ++f) {
            f16x8 a;
#pragma unroll
            for (int j = 0; j < 8; ++j)
                a[j] = (_Float16)vf_w0[row * 64 + f * 32 + g4 * 8 + j];
            aw0[f] = a;
        }
#pragma unroll
        for (int f = 0; f < 4; ++f) {
            f16x8 a;
#pragma unroll
            for (int j = 0; j < 8; ++j)
                a[j] = (_Float16)vf_wh[row * 128 + f * 32 + g4 * 8 + j];
            awh[f] = a;
        }
#pragma unroll
        for (int i = 0; i < 8; ++i) {
            const int rq = (wv * 8 + i) * 16 + m16;
#pragma unroll
            for (int f = 0; f < 4; ++f) {
                f16x8 a;
#pragma unroll
                for (int j = 0; j < 8; ++j)
                    a[j] = (_Float16)vf_wout[(size_t)rq * 128 + f * 32 + g4 * 8 + j];
                awq[i][f] = a;
            }
        }
    }
    const float4 bw0 = *(const float4*)(vf_b0 + wv * 16 + g4 * 4);
    const float4 bwh = *(const float4*)(vf_bh + wv * 16 + g4 * 4);
    const float bo0 = vf_bout[2 * tid], bo1 = vf_bout[2 * tid + 1];
    const int l_idx = tid >> 3;       // output row l of V(64,16); 2*tid == l_idx*16+c0
    const int c0 = 2 * (tid & 7);     // dx columns c0, c0+1

    const size_t cofs = (size_t)b * 127 * 16;

// ys phase for stage S>0: 64 threads build stage input, then barrier.
#define KS(m) s_k[m][tid]
#define YS_PHASE(...)                                                          \
    do {                                                                       \
        if (tid < 64) {                                                        \
            float yv = s_y[tid];                                               \
            __VA_ARGS__;                                                       \
            s_ysbh[tid] = __float2half_rn(yv);                                 \
        }                                                                      \
        __syncthreads();                                                       \
    } while (0)

// MFMA stage body: W0 -> h1 ; Wh -> h2 ; Wout -> V ; epilogue -> k[S]
// B-operand is broadcast (all 16 cols = same vector); C/D col index (m16)
// is redundant, row = g4*4 + reg. Writers: m16 == 0 lanes.
#define MFMA_STAGE(S, CC)                                                      \
    do {                                                                       \
        {   /* W0: ys(64) -> h1(128), rows wv*16..+15 */                       \
            f16x8 b0 = *(const f16x8*)((const char*)s_ysbh + g4 * 16);         \
            f16x8 b1 = *(const f16x8*)((const char*)s_ysbh + 64 + g4 * 16);    \
            f32x4 acc = {0.f, 0.f, 0.f, 0.f};                                  \
            acc = mfma16(aw0[0], b0, acc);                                     \
            acc = mfma16(aw0[1], b1, acc);                                     \
            if (m16 == 0) {                                                    \
                __half q0 = __float2half_rn(softplus_f(acc[0] + bw0.x));       \
                __half q1 = __float2half_rn(softplus_f(acc[1] + bw0.y));       \
                __half q2 = __float2half_rn(softplus_f(acc[2] + bw0.z));       \
                __half q3 = __float2half_rn(softplus_f(acc[3] + bw0.w));       \
                uint2 pk;                                                      \
                pk.x = (unsigned)__half_as_ushort(q0) | ((unsigned)__half_as_ushort(q1) << 16); \
                pk.y = (unsigned)__half_as_ushort(q2) | ((unsigned)__half_as_ushort(q3) << 16); \
                *(uint2*)(&s_h1h[wv * 16 + g4 * 4]) = pk;                      \
            }                                                                  \
        }                                                                      \
        __syncthreads();                                                       \
        {   /* Wh: h1 -> h2 */                                                 \
            f32x4 acc = {0.f, 0.f, 0.f, 0.f};                                  \
            _Pragma("unroll")                                                  \
            for (int f = 0; f < 4; ++f) {                                      \
                f16x8 bf = *(const f16x8*)((const char*)s_h1h + f * 64 + g4 * 16); \
                acc = mfma16(awh[f], bf, acc);                                 \
            }                                                                  \
            if (m16 == 0) {                                                    \
                __half q0 = __float2half_rn(softplus_f(acc[0] + bwh.x));       \
                __half q1 = __float2half_rn(softplus_f(acc[1] + bwh.y));       \
                __half q2 = __float2half_rn(softplus_f(acc[2] + bwh.z));       \
                __half q3 = __float2half_rn(softplus_f(acc[3] + bwh.w));       \
                uint2 pk;                                                      \
                pk.x = (unsigned)__half_as_ushort(q0) | ((unsigned)__half_as_ushort(q1) << 16); \
                pk.y = (unsigned)__half_as_ushort(q2) | ((unsigned)__half_as_ushort(q3) << 16); \
                *(uint2*)(&s_h2h[wv * 16 + g4 * 4]) = pk;                      \
            }                                                                  \
        }                                                                      \
        __syncthreads();                                                       \
        {   /* Wout: h2 -> raw V rows (wv*8+i)*16 + g4*4.. */                  \
            f16x8 bf[4];                                                       \
            _Pragma("unroll")                                                  \
            for (int f = 0; f < 4; ++f)                                        \
                bf[f] = *(const f16x8*)((const char*)s_h2h + f * 64 + g4 * 16); \
            _Pragma("unroll")                                                  \
            for (int i = 0; i < 8; ++i) {                                      \
                f32x4 acc = {0.f, 0.f, 0.f, 0.f};                              \
                acc = mfma16(awq[i][0], bf[0], acc);                           \
                acc = mfma16(awq[i][1], bf[1], acc);                           \
                acc = mfma16(awq[i][2], bf[2], acc);                           \
                acc = mfma16(awq[i][3], bf[3], acc);                           \
                if (m16 == 0)                                                  \
                    *(f32x4*)(&s_V[(wv * 8 + i) * 16 + g4 * 4]) = acc;         \
            }                                                                  \
        }                                                                      \
        __syncthreads();                                                       \
        {   /* epilogue: tanh + dx-contract -> k[S] (512 threads) */           \
            float2 vp = *(const float2*)(&s_V[l_idx * 16 + c0]);               \
            float v0 = tanh_f(vp.x + bo0);                                     \
            float v1 = tanh_f(vp.y + bo1);                                     \
            float frac = fmaf((CC), hstep, f0);                                \
            float dx0 = fmaf(3.f * s_di[c0], frac * frac,                      \
                             fmaf(2.f * s_ci[c0], frac, s_bi[c0]));            \
            float dx1 = fmaf(3.f * s_di[c0 + 1], frac * frac,                  \
                             fmaf(2.f * s_ci[c0 + 1], frac, s_bi[c0 + 1]));    \
            float p = fmaf(v0, dx0, v1 * dx1);                                 \
            p = dpp_add<0xB1>(p);                                              \
            p = dpp_add<0x4E>(p);                                              \
            p = dpp_add<0x141>(p);                                             \
            if ((tid & 7) == 0) s_k[S][l_idx] = p;                             \
        }                                                                      \
        __syncthreads();                                                       \
    } while (0)

    // ---- main ODE loop: 127 intervals x 2 substeps x 6 stages ----
#pragma unroll 1
    for (int t = 0; t < 127; ++t) {
        // coef loads: first use (stage-0 epilogue) is 3 barriers away
        if (tid < 16) s_bi[tid] = coef_b[cofs + t * 16 + tid];
        else if (tid < 32) s_ci[tid - 16] = coef_c[cofs + t * 16 + (tid - 16)];
        else if (tid < 48) s_di[tid - 32] = coef_d[cofs + t * 16 + (tid - 32)];
        const float t0 = timestamps[t], t1 = timestamps[t + 1];
        const float hstep = (t1 - t0) * 0.5f;

#pragma unroll 1
        for (int sub = 0; sub < 2; ++sub) {
            const float f0 = (float)sub * hstep;

            // stage 0: s_ysbh already holds y (from init / y-update)
            MFMA_STAGE(0, 0.f);
            YS_PHASE(yv = fmaf(hstep * 0.2f, KS(0), yv));
            MFMA_STAGE(1, 0.2f);
            YS_PHASE(yv = fmaf(hstep, fmaf(3.f / 40.f, KS(0), (9.f / 40.f) * KS(1)), yv));
            MFMA_STAGE(2, 0.3f);
            YS_PHASE(yv = fmaf(hstep, fmaf(44.f / 45.f, KS(0),
                          fmaf(-56.f / 15.f, KS(1), (32.f / 9.f) * KS(2))), yv));
            MFMA_STAGE(3, 0.8f);
            YS_PHASE(yv = fmaf(hstep, fmaf(19372.f / 6561.f, KS(0),
                          fmaf(-25360.f / 2187.f, KS(1),
                          fmaf(64448.f / 6561.f, KS(2), (-212.f / 729.f) * KS(3)))), yv));
            MFMA_STAGE(4, 8.f / 9.f);
            YS_PHASE(yv = fmaf(hstep, fmaf(9017.f / 3168.f, KS(0),
                          fmaf(-355.f / 33.f, KS(1),
                          fmaf(46732.f / 5247.f, KS(2),
                          fmaf(49.f / 176.f, KS(3), (-5103.f / 18656.f) * KS(4))))), yv));
            MFMA_STAGE(5, 1.f);

            // y update (Dopri5 b-weights; b[1]=0); primes s_ysbh for next stage-0
            if (tid < 64) {
                float yv = s_y[tid];
                yv = fmaf(hstep * (35.f / 384.f), s_k[0][tid], yv);
                yv = fmaf(hstep * (500.f / 1113.f), s_k[2][tid], yv);
                yv = fmaf(hstep * (125.f / 192.f), s_k[3][tid], yv);
                yv = fmaf(hstep * (-2187.f / 6784.f), s_k[4][tid], yv);
                yv = fmaf(hstep * (11.f / 84.f), s_k[5][tid], yv);
                s_y[tid] = yv;
                s_ysbh[tid] = __float2half_rn(yv);
                if (sub == 1) s_ysall[t + 1][tid] = yv;
            }
            __syncthreads();
        } // sub
    } // t

    // ---- decoder: per timestep 64 -> 32 -> 32 -> 8 (relu, relu, ident) ----
    const int wid = tid >> 6, lane2 = tid & 63;
    for (int t = wid; t < 128; t += 8) {
        const float* yy = s_ysall[t];
        float h1d = 0.f;
        if (lane2 < 32) {
            float a = dec_b0[lane2];
            const float* wr = dec_w0 + lane2 * 64;
            for (int j = 0; j < 64; ++j) a = fmaf(wr[j], yy[j], a);
            h1d = fmaxf(a, 0.f);
        }
        float a2 = (lane2 < 32) ? dec_bh[lane2] : 0.f;
#pragma unroll 8
        for (int j = 0; j < 32; ++j) {
            float hj = __shfl(h1d, j);
            if (lane2 < 32) a2 = fmaf(dec_wh[lane2 * 32 + j], hj, a2);
        }
        float h2d = fmaxf(a2, 0.f);
        float o = (lane2 < 8) ? dec_bout[lane2] : 0.f;
#pragma unroll 8
        for (int j = 0; j < 32; ++j) {
            float hj = __shfl(h2d, j);
            if (lane2 < 8) o = fmaf(dec_wout[lane2 * 32 + j], hj, o);
        }
        if (lane2 < 8) out[(size_t)b * 1024 + t * 8 + lane2] = o;
    }
}

extern "C" void kernel_launch(void* const* d_in, const int* in_sizes, int n_in,
                              void* d_out, int out_size, void* d_ws, size_t ws_size,
                              hipStream_t stream) {
    const float* p[29];
    for (int i = 0; i < 29; ++i) p[i] = (const float*)d_in[i];
    ncde_kernel<<<256, TPB, 0, stream>>>(
        p[0], p[1], p[2], p[3], p[4], p[5], p[6], p[7], p[8], p[9], p[10],
        p[11], p[12], p[13], p[14], p[15], p[16], p[17], p[18], p[19], p[20],
        p[21], p[22], p[23], p[24], p[25], p[26], p[27], p[28],
        (float*)d_out);
}